// Round 12
// baseline (1005.319 us; speedup 1.0000x reference)
//
#include <hip/hip_runtime.h>
#include <hip/hip_bf16.h>

// GraphFilter: out = sum_k (S^k x) @ W_k,  S = symmetric scatter-add adjacency
// N=100000, E=3200000, FIN=FOUT=256, K=4.
// Round 12: attack spmm's 736MB/hop L2-miss traffic (the 3x222us = 71% of
// total, purely traffic-bound at ~3.5 TB/s). (1) sort_adj: per-row coarse
// counting sort of neighbor lists (nbr>>12, 32 buckets); (2) persistent spmm
// (2048 blocks, strided rows): all 8192 waves sweep sorted src-space in
// phase -> instantaneous band ~few MB fits per-XCD L2. (3) fuse
// convert_x||chunk_count||wmax into one launch. gemm/CSR rest unchanged.

#define NNODES 100000
#define NEDGES 3200000
#define FOUTF  256
#define MPAD   100096          // 782 * 128
#define MTILES 782
#define NB     782             // node buckets: node >> 7
#define NCHUNK 1024
#define CHUNK  3125            // 1024*3125 = 3.2M edges

typedef __attribute__((ext_vector_type(4))) int   i32x4;
typedef __attribute__((ext_vector_type(4))) float f32x4;

__device__ __forceinline__ void async_ld16(const void* g, void* l) {
  __builtin_amdgcn_global_load_lds(
      (const __attribute__((address_space(1))) unsigned int*)g,
      (__attribute__((address_space(3))) unsigned int*)l, 16, 0, 0);
}

// ---------------- fused front kernel: convert_x || chunk_count || wmax ------
// blocks [0,25000): convert_x; [25000,26024): chunk_count; [26024,26280): wmax.
__global__ __launch_bounds__(256)
void front_kernel(const float* __restrict__ x,
                  unsigned char* __restrict__ g0, float* __restrict__ sc0,
                  const int* __restrict__ ei, int* __restrict__ cntg,
                  const float* __restrict__ w, unsigned int* __restrict__ dWmax) {
  __shared__ int h[NB];
  const int bid = blockIdx.x;
  if (bid < 25000) {
    // ---- convert_x: wave per row, int8 rowmax quant ----
    const int row = (bid * 256 + threadIdx.x) >> 6;
    const int lane = threadIdx.x & 63;
    if (row >= NNODES) return;
    float4 xv = *(const float4*)&x[(size_t)row * 256 + (lane << 2)];
    float m = fmaxf(fmaxf(fabsf(xv.x), fabsf(xv.y)), fmaxf(fabsf(xv.z), fabsf(xv.w)));
    #pragma unroll
    for (int i = 1; i < 64; i <<= 1) m = fmaxf(m, __shfl_xor(m, i, 64));
    float inv = (m > 0.f) ? 127.f / m : 0.f;
    int q0 = (int)__builtin_rintf(xv.x * inv);
    int q1 = (int)__builtin_rintf(xv.y * inv);
    int q2 = (int)__builtin_rintf(xv.z * inv);
    int q3 = (int)__builtin_rintf(xv.w * inv);
    *(unsigned int*)(g0 + (size_t)row * 256 + (lane << 2)) =
        ((unsigned)q0 & 255u) | (((unsigned)q1 & 255u) << 8) |
        (((unsigned)q2 & 255u) << 16) | (((unsigned)q3 & 255u) << 24);
    if (lane == 0) sc0[row] = m * (1.f / 127.f);
  } else if (bid < 26024) {
    // ---- chunk_count -> cntg[chunk][bucket] ----
    const int b = bid - 25000;
    for (int i = threadIdx.x; i < NB; i += 256) h[i] = 0;
    __syncthreads();
    const int e0 = b * CHUNK;
    const int e1 = (e0 + CHUNK < NEDGES) ? e0 + CHUNK : NEDGES;
    for (int e = e0 + threadIdx.x; e < e1; e += 256) {
      int s = ei[e];
      int d = ei[NEDGES + e];
      atomicAdd(&h[d >> 7], 1);
      atomicAdd(&h[s >> 7], 1);
    }
    __syncthreads();
    for (int i = threadIdx.x; i < NB; i += 256)
      cntg[b * NB + i] = h[i];
  } else {
    // ---- wmax: per-slot |W| max via atomicMax ----
    const int b = bid - 26024;
    const int k = b >> 6;
    const int chunk = b & 63;
    const float* wk = w + (size_t)k * 65536 + chunk * 1024;
    float m = 0.f;
    #pragma unroll
    for (int i = 0; i < 4; ++i) m = fmaxf(m, fabsf(wk[threadIdx.x + i * 256]));
    #pragma unroll
    for (int i = 1; i < 64; i <<= 1) m = fmaxf(m, __shfl_xor(m, i, 64));
    if (threadIdx.x == 0) h[0] = 0;
    __syncthreads();
    if ((threadIdx.x & 63) == 0) atomicMax(&h[0], __float_as_int(m));
    __syncthreads();
    if (threadIdx.x == 0) atomicMax(&dWmax[k], (unsigned int)h[0]);
  }
}

// ---------------- CSR back-end (r9/r11 config) ----------------

__global__ __launch_bounds__(256)
void scan_chunks_kernel(int* __restrict__ cntg, int* __restrict__ tot) {
  __shared__ int ws2[4];
  const int v = blockIdx.x;
  const int t = threadIdx.x, lane = t & 63, wv = t >> 6;
  int c[4];
  int sum = 0;
  #pragma unroll
  for (int i = 0; i < 4; ++i) { c[i] = cntg[(4 * t + i) * NB + v]; sum += c[i]; }
  int s = sum;
  #pragma unroll
  for (int off = 1; off < 64; off <<= 1) {
    int tmp = __shfl_up(s, off, 64);
    if (lane >= off) s += tmp;
  }
  if (lane == 63) ws2[wv] = s;
  __syncthreads();
  int wpre = 0;
  #pragma unroll
  for (int k = 0; k < 4; ++k) wpre += (k < wv) ? ws2[k] : 0;
  int run = wpre + s - sum;
  #pragma unroll
  for (int i = 0; i < 4; ++i) { int tmp = c[i]; cntg[(4 * t + i) * NB + v] = run; run += tmp; }
  if (t == 255) tot[v] = wpre + s;
}

__global__ __launch_bounds__(1024)
void base_scan_kernel(const int* __restrict__ tot, int* __restrict__ bbase) {
  __shared__ int ws[16];
  int t = threadIdx.x, lane = t & 63, wv = t >> 6;
  int v = (t < NB) ? tot[t] : 0;
  int s = v;
  #pragma unroll
  for (int off = 1; off < 64; off <<= 1) {
    int tmp = __shfl_up(s, off, 64);
    if (lane >= off) s += tmp;
  }
  if (lane == 63) ws[wv] = s;
  __syncthreads();
  if (t == 0) {
    int run = 0;
    #pragma unroll
    for (int k = 0; k < 16; ++k) { int tmp = ws[k]; ws[k] = run; run += tmp; }
  }
  __syncthreads();
  int excl = s + ws[wv] - v;
  if (t < NB) bbase[t] = excl;
  if (t == NB) bbase[NB] = excl;
}

// packed binned entry: (owner&127)<<17 | nbr
__global__ __launch_bounds__(256)
void fill_kernel(const int* __restrict__ ei, const int* __restrict__ cntg,
                 const int* __restrict__ bbase, unsigned int* __restrict__ binned) {
  __shared__ int cur[NB];
  const int b = blockIdx.x;
  for (int i = threadIdx.x; i < NB; i += 256)
    cur[i] = bbase[i] + cntg[b * NB + i];
  __syncthreads();
  const int e0 = b * CHUNK;
  const int e1 = (e0 + CHUNK < NEDGES) ? e0 + CHUNK : NEDGES;
  for (int e = e0 + threadIdx.x; e < e1; e += 256) {
    int s = ei[e];
    int d = ei[NEDGES + e];
    int p = atomicAdd(&cur[d >> 7], 1);
    binned[p] = ((unsigned int)(d & 127) << 17) | (unsigned int)s;
    int q = atomicAdd(&cur[s >> 7], 1);
    binned[q] = ((unsigned int)(s & 127) << 17) | (unsigned int)d;
  }
}

// adj entries are PRE-SCALED q-row byte offsets (nbr * 256).
__global__ __launch_bounds__(256)
void bucket_csr_kernel(const unsigned int* __restrict__ binned,
                       const int* __restrict__ bbase,
                       int* __restrict__ row_ptr, int* __restrict__ adj) {
  __shared__ int cnt[128];
  __shared__ int cur[128];
  const int b = blockIdx.x;
  const int node0 = b << 7;
  const int base = bbase[b];
  const int end = bbase[b + 1];
  const int tid = threadIdx.x;
  if (tid < 128) cnt[tid] = 0;
  __syncthreads();
  for (int i = base + tid; i < end; i += 256) {
    unsigned int v = binned[i];
    atomicAdd(&cnt[v >> 17], 1);
  }
  __syncthreads();
  if (tid < 128) {
    int ex = 0;
    #pragma unroll 8
    for (int j = 0; j < 128; ++j) {
      int c = cnt[j];
      ex += (j < tid) ? c : 0;
    }
    int node = node0 + tid;
    if (node < NNODES) row_ptr[node] = base + ex;
    cur[tid] = base + ex;
  }
  if (tid == 0 && b == NB - 1) row_ptr[NNODES] = end;
  __syncthreads();
  for (int i = base + tid; i < end; i += 256) {
    unsigned int v = binned[i];
    int nbr = (int)(v & 0x1FFFFu);
    int p = atomicAdd(&cur[v >> 17], 1);
    adj[p] = nbr << 8;
  }
}

// ---------------- sort_adj: per-row coarse counting sort (nbr>>12) ----------
// Wave per node; 32 buckets of 4096 nodes; rows with deg>256 left unsorted
// (correctness unaffected). Enables the synchronized src-space sweep in spmm.
__global__ __launch_bounds__(256)
void sort_adj_kernel(const int* __restrict__ row_ptr, int* __restrict__ adj) {
  __shared__ int cnt[4][32];
  __shared__ int cur[4][32];
  const int wv = threadIdx.x >> 6;
  const int lane = threadIdx.x & 63;
  const int wid = blockIdx.x * 4 + wv;
  if (wid >= NNODES) return;
  const int beg = row_ptr[wid];
  const int deg = row_ptr[wid + 1] - beg;
  if (deg > 256) return;
  if (lane < 32) cnt[wv][lane] = 0;
  int v[4];
  #pragma unroll
  for (int i = 0; i < 4; ++i) {
    int idx = lane + 64 * i;
    v[i] = (idx < deg) ? adj[beg + idx] : -1;
  }
  #pragma unroll
  for (int i = 0; i < 4; ++i)
    if (v[i] >= 0) atomicAdd(&cnt[wv][((unsigned)v[i]) >> 20], 1);
  if (lane < 32) {
    int c = cnt[wv][lane];
    int s = c;
    #pragma unroll
    for (int off = 1; off < 32; off <<= 1) {
      int tmp = __shfl_up(s, off, 32);
      if ((lane & 31) >= off) s += tmp;
    }
    cur[wv][lane] = s - c;        // exclusive prefix
  }
  #pragma unroll
  for (int i = 0; i < 4; ++i) {
    if (v[i] >= 0) {
      int pos = atomicAdd(&cur[wv][((unsigned)v[i]) >> 20], 1);
      adj[beg + pos] = v[i];
    }
  }
}

// ---------------- quantw ----------------
__global__ void quantw_kernel(const float* __restrict__ w,
                              const unsigned int* __restrict__ dWmax,
                              signed char* __restrict__ W8) {
  int idx = blockIdx.x * 256 + threadIdx.x;
  int k = idx >> 16, f = (idx >> 8) & 255, o = idx & 255;
  float mx = __uint_as_float(dWmax[k]);
  float inv = (mx > 0.f) ? 127.f / mx : 0.f;
  W8[(size_t)k * 65536 + o * 256 + f] = (signed char)(int)__builtin_rintf(w[idx] * inv);
}

// ---------------- SpMM int8, persistent (2048 blocks, strided rows) ---------
// All 8192 waves co-resident; batch i = rows [i*8192,(i+1)*8192) processed
// simultaneously; sorted adj -> synchronized sweep of src-space.

#define DECQ(vv, ss)                                        \
  { acc0 += (ss) * (float)((vv) & 255u);                    \
    acc1 += (ss) * (float)(((vv) >> 8) & 255u);             \
    acc2 += (ss) * (float)(((vv) >> 16) & 255u);            \
    acc3 += (ss) * (float)((vv) >> 24);                     \
    ssum += (ss); }

__global__ __launch_bounds__(256)
void spmm_q8_kernel(const unsigned char* __restrict__ gin,   // [N][256] int8
                    const float* __restrict__ sin,           // [N] scales
                    unsigned char* __restrict__ gout,        // [N][256] int8
                    float* __restrict__ sout,                // [N]
                    const int* __restrict__ row_ptr,
                    const int* __restrict__ adjb) {
  const int wv = threadIdx.x >> 6;
  const int lane = threadIdx.x & 63;
  const int wbase = blockIdx.x * 4 + wv;
  const int lb = lane << 2;
  const char* scb = (const char*)sin;

  for (int wid0 = wbase; wid0 < NNODES; wid0 += 8192) {
    const int wid = __builtin_amdgcn_readfirstlane(wid0);
    const int beg = row_ptr[wid];
    const int end = row_ptr[wid + 1];

    float acc0 = 0.f, acc1 = 0.f, acc2 = 0.f, acc3 = 0.f, ssum = 0.f;
    int j = beg;
    for (; j + 4 <= end; j += 4) {
      int o0 = adjb[j + 0], o1 = adjb[j + 1], o2 = adjb[j + 2], o3 = adjb[j + 3];
      float s0 = *(const float*)(scb + (o0 >> 6));
      float s1 = *(const float*)(scb + (o1 >> 6));
      float s2 = *(const float*)(scb + (o2 >> 6));
      float s3 = *(const float*)(scb + (o3 >> 6));
      unsigned int v0 = *(const unsigned int*)(gin + o0 + lb) ^ 0x80808080u;
      unsigned int v1 = *(const unsigned int*)(gin + o1 + lb) ^ 0x80808080u;
      unsigned int v2 = *(const unsigned int*)(gin + o2 + lb) ^ 0x80808080u;
      unsigned int v3 = *(const unsigned int*)(gin + o3 + lb) ^ 0x80808080u;
      DECQ(v0, s0); DECQ(v1, s1); DECQ(v2, s2); DECQ(v3, s3);
    }
    for (; j < end; ++j) {
      int o = adjb[j];
      float s = *(const float*)(scb + (o >> 6));
      unsigned int v = *(const unsigned int*)(gin + o + lb) ^ 0x80808080u;
      DECQ(v, s);
    }

    const float bias = 128.f * ssum;
    const float a0 = acc0 - bias;
    const float a1 = acc1 - bias;
    const float a2 = acc2 - bias;
    const float a3 = acc3 - bias;

    float m = fmaxf(fmaxf(fabsf(a0), fabsf(a1)), fmaxf(fabsf(a2), fabsf(a3)));
    #pragma unroll
    for (int i = 1; i < 64; i <<= 1) m = fmaxf(m, __shfl_xor(m, i, 64));
    float inv = (m > 0.f) ? 127.f / m : 0.f;
    int q0 = (int)__builtin_rintf(a0 * inv);
    int q1 = (int)__builtin_rintf(a1 * inv);
    int q2 = (int)__builtin_rintf(a2 * inv);
    int q3 = (int)__builtin_rintf(a3 * inv);
    *(unsigned int*)(gout + (size_t)wid * 256 + lb) =
        ((unsigned)q0 & 255u) | (((unsigned)q1 & 255u) << 8) |
        (((unsigned)q2 & 255u) << 16) | (((unsigned)q3 & 255u) << 24);
    if (lane == 0) sout[wid] = m * (1.f / 127.f);
  }
}

// ---------------- GEMM: 4x { [128,256]i8 @ [256,256]i8 } -> fp32 ----------------
// r11 version (LDS XOR-swizzle both-sides; private-LDS staged full-line
// C stores).

__global__ __launch_bounds__(512)
void gemm_i8_kernel(const unsigned char* __restrict__ q0p,
                    const unsigned char* __restrict__ q1p,
                    const unsigned char* __restrict__ q2p,
                    const unsigned char* __restrict__ q3p,
                    const float* __restrict__ s0p,
                    const float* __restrict__ s1p,
                    const float* __restrict__ s2p,
                    const float* __restrict__ s3p,
                    const signed char* __restrict__ W8,     // [4][256][256]
                    const unsigned int* __restrict__ dWmax, // [4]
                    float* __restrict__ C) {                // [NNODES][256]
  __shared__ __align__(16) unsigned char smem[49152];       // As 16K | Bs 32K
  unsigned char* As = smem;
  unsigned char* Bs = smem + 16384;
  const int tid = threadIdx.x;
  const int lane = tid & 63;
  const int wave = tid >> 6;
  const int wr = wave >> 2;
  const int wc = wave & 3;
  const int rowA_base = blockIdx.x * 128;

  const unsigned char* qs[4] = {q0p, q1p, q2p, q3p};
  const float* scs[4] = {s0p, s1p, s2p, s3p};

  f32x4 accf[4][4] = {};

  #pragma unroll
  for (int k = 0; k < 4; ++k) {
    const unsigned char* Qk = qs[k];
    const signed char* Wk = W8 + (size_t)k * 65536;
    i32x4 acci[4][4] = {};
    #pragma unroll
    for (int kc = 0; kc < 2; ++kc) {
      __syncthreads();
      #pragma unroll
      for (int i = 0; i < 2; ++i) {
        int slot = tid + 512 * i;
        int row = slot >> 3;
        int col = ((slot & 7) << 4) ^ ((row & 7) << 4);
        async_ld16(Qk + (size_t)(rowA_base + row) * 256 + kc * 128 + col,
                   &As[slot * 16]);
      }
      #pragma unroll
      for (int i = 0; i < 4; ++i) {
        int slot = tid + 512 * i;
        int row = slot >> 3;
        int col = ((slot & 7) << 4) ^ ((row & 7) << 4);
        async_ld16(Wk + (size_t)row * 256 + kc * 128 + col, &Bs[slot * 16]);
      }
      __syncthreads();
      #pragma unroll
      for (int kk = 0; kk < 2; ++kk) {
        const int kb = kk * 64 + ((lane >> 4) << 4);
        i32x4 a[4], b[4];
        #pragma unroll
        for (int m = 0; m < 4; ++m) {
          int row = wr * 64 + m * 16 + (lane & 15);
          a[m] = *(const i32x4*)&As[row * 128 + (kb ^ ((row & 7) << 4))];
        }
        #pragma unroll
        for (int n = 0; n < 4; ++n) {
          int row = wc * 64 + n * 16 + (lane & 15);
          b[n] = *(const i32x4*)&Bs[row * 128 + (kb ^ ((row & 7) << 4))];
        }
        #pragma unroll
        for (int m = 0; m < 4; ++m) {
          #pragma unroll
          for (int n = 0; n < 4; ++n)
            acci[m][n] = __builtin_amdgcn_mfma_i32_16x16x64_i8(a[m], b[n], acci[m][n], 0, 0, 0);
        }
      }
    }
    const float dWk = __uint_as_float(dWmax[k]) * (1.f / 127.f);
    const float* sk = scs[k];
    #pragma unroll
    for (int m = 0; m < 4; ++m) {
      #pragma unroll
      for (int j = 0; j < 4; ++j) {
        int r = rowA_base + wr * 64 + ((lane >> 4) << 2) + m * 16 + j;
        float s = sk[r] * dWk;
        #pragma unroll
        for (int n = 0; n < 4; ++n)
          accf[m][n][j] += s * (float)acci[m][n][j];
      }
    }
  }

  __syncthreads();
  float* myCs = (float*)smem + wave * 1056;   // [16 rows][stride 66]
  #pragma unroll
  for (int m = 0; m < 4; ++m) {
    #pragma unroll
    for (int n = 0; n < 4; ++n) {
      #pragma unroll
      for (int j = 0; j < 4; ++j)
        myCs[(((lane >> 4) << 2) | j) * 66 + (lane & 15) + n * 16] = accf[m][n][j];
    }
    #pragma unroll
    for (int it = 0; it < 4; ++it) {
      int row = it * 4 + (lane >> 4);
      f32x4 v = *(const f32x4*)&myCs[row * 66 + ((lane & 15) << 2)];
      int r = rowA_base + wr * 64 + m * 16 + row;
      if (r < NNODES)
        *(f32x4*)&C[(size_t)r * FOUTF + wc * 64 + ((lane & 15) << 2)] = v;
    }
  }
}

// ---------------- launch ----------------

extern "C" void kernel_launch(void* const* d_in, const int* in_sizes, int n_in,
                              void* d_out, int out_size, void* d_ws, size_t ws_size,
                              hipStream_t stream) {
  (void)in_sizes; (void)n_in; (void)out_size; (void)ws_size;
  const float* x  = (const float*)d_in[0];
  const int*   ei = (const int*)d_in[1];
  const float* w  = (const float*)d_in[2];
  float* out = (float*)d_out;

  char* ws = (char*)d_ws;
  size_t off = 0;
  auto carve = [&](size_t bytes) -> void* {
    void* p = ws + off;
    off = (off + bytes + 255) & ~(size_t)255;
    return p;
  };
  unsigned char* gA = (unsigned char*)carve((size_t)MPAD * 256);   // 25.6 MB
  unsigned char* gB = (unsigned char*)carve((size_t)MPAD * 256);
  unsigned char* gC = (unsigned char*)carve((size_t)MPAD * 256);
  unsigned char* gD = (unsigned char*)carve((size_t)MPAD * 256);
  float* scA        = (float*)carve((size_t)MPAD * 4);
  float* scB        = (float*)carve((size_t)MPAD * 4);
  float* scC        = (float*)carve((size_t)MPAD * 4);
  float* scD        = (float*)carve((size_t)MPAD * 4);
  signed char* W8   = (signed char*)carve((size_t)4 * 65536);
  unsigned int* dWmax = (unsigned int*)carve(4 * 4);
  int* row_ptr      = (int*)carve((size_t)(NNODES + 1) * 4);
  int* adj          = (int*)carve((size_t)2 * NEDGES * 4);         // 25.6 MB
  int* cntg         = (int*)carve((size_t)NCHUNK * NB * 4);        // 3.2 MB
  int* tot          = (int*)carve((size_t)NB * 4);
  int* bbase        = (int*)carve((size_t)(NB + 1) * 4);
  // binned (2E * 4B = 25.6 MB) aliases gD: fully consumed by bucket_csr
  // before hop3 writes q3 into gD (stream-ordered).
  unsigned int* binned = (unsigned int*)gD;

  hipMemsetAsync(dWmax, 0, 16, stream);

  front_kernel<<<26280, 256, 0, stream>>>(x, gA, scA, ei, cntg, w, dWmax);
  scan_chunks_kernel<<<NB, 256, 0, stream>>>(cntg, tot);
  base_scan_kernel<<<1, 1024, 0, stream>>>(tot, bbase);
  fill_kernel<<<NCHUNK, 256, 0, stream>>>(ei, cntg, bbase, binned);
  bucket_csr_kernel<<<NB, 256, 0, stream>>>(binned, bbase, row_ptr, adj);
  sort_adj_kernel<<<25000, 256, 0, stream>>>(row_ptr, adj);
  quantw_kernel<<<1024, 256, 0, stream>>>(w, dWmax, W8);

  // hop1: q0->q1; hop2: q1->q2; hop3: q2->q3  (persistent, 8192 waves)
  spmm_q8_kernel<<<2048, 256, 0, stream>>>(gA, scA, gB, scB, row_ptr, adj);
  spmm_q8_kernel<<<2048, 256, 0, stream>>>(gB, scB, gC, scC, row_ptr, adj);
  spmm_q8_kernel<<<2048, 256, 0, stream>>>(gC, scC, gD, scD, row_ptr, adj);

  gemm_i8_kernel<<<MTILES, 512, 0, stream>>>(gA, gB, gC, gD, scA, scB, scC, scD,
                                             W8, dWmax, out);
}

// Round 13
// 914.108 us; speedup vs baseline: 1.0998x; 1.0998x over previous
//
#include <hip/hip_runtime.h>
#include <hip/hip_bf16.h>

// GraphFilter: out = sum_k (S^k x) @ W_k,  S = symmetric scatter-add adjacency
// N=100000, E=3200000, FIN=FOUT=256, K=4.
// Round 13: revert r12's sort/persistent spmm (falsified: FETCH unchanged,
// uniform-random graph has no reuse-distance structure). Keep r12's fused
// front (convert_x||chunk_count||wmax). spmm: r11 shape + UNROLL 8 (8 gathers
// + scales in flight before decode) to recover fetch-issue rate (3.31 ->
// ~3.6 TB/s, v1 demonstrated 3.65+). CSR back-end, gemm (r11) unchanged.

#define NNODES 100000
#define NEDGES 3200000
#define FOUTF  256
#define MPAD   100096          // 782 * 128
#define MTILES 782
#define NB     782             // node buckets: node >> 7
#define NCHUNK 1024
#define CHUNK  3125            // 1024*3125 = 3.2M edges

typedef __attribute__((ext_vector_type(4))) int   i32x4;
typedef __attribute__((ext_vector_type(4))) float f32x4;

__device__ __forceinline__ void async_ld16(const void* g, void* l) {
  __builtin_amdgcn_global_load_lds(
      (const __attribute__((address_space(1))) unsigned int*)g,
      (__attribute__((address_space(3))) unsigned int*)l, 16, 0, 0);
}

// ---------------- fused front kernel: convert_x || chunk_count || wmax ------
// blocks [0,25000): convert_x; [25000,26024): chunk_count; [26024,26280): wmax.
__global__ __launch_bounds__(256)
void front_kernel(const float* __restrict__ x,
                  unsigned char* __restrict__ g0, float* __restrict__ sc0,
                  const int* __restrict__ ei, int* __restrict__ cntg,
                  const float* __restrict__ w, unsigned int* __restrict__ dWmax) {
  __shared__ int h[NB];
  const int bid = blockIdx.x;
  if (bid < 25000) {
    const int row = (bid * 256 + threadIdx.x) >> 6;
    const int lane = threadIdx.x & 63;
    if (row >= NNODES) return;
    float4 xv = *(const float4*)&x[(size_t)row * 256 + (lane << 2)];
    float m = fmaxf(fmaxf(fabsf(xv.x), fabsf(xv.y)), fmaxf(fabsf(xv.z), fabsf(xv.w)));
    #pragma unroll
    for (int i = 1; i < 64; i <<= 1) m = fmaxf(m, __shfl_xor(m, i, 64));
    float inv = (m > 0.f) ? 127.f / m : 0.f;
    int q0 = (int)__builtin_rintf(xv.x * inv);
    int q1 = (int)__builtin_rintf(xv.y * inv);
    int q2 = (int)__builtin_rintf(xv.z * inv);
    int q3 = (int)__builtin_rintf(xv.w * inv);
    *(unsigned int*)(g0 + (size_t)row * 256 + (lane << 2)) =
        ((unsigned)q0 & 255u) | (((unsigned)q1 & 255u) << 8) |
        (((unsigned)q2 & 255u) << 16) | (((unsigned)q3 & 255u) << 24);
    if (lane == 0) sc0[row] = m * (1.f / 127.f);
  } else if (bid < 26024) {
    const int b = bid - 25000;
    for (int i = threadIdx.x; i < NB; i += 256) h[i] = 0;
    __syncthreads();
    const int e0 = b * CHUNK;
    const int e1 = (e0 + CHUNK < NEDGES) ? e0 + CHUNK : NEDGES;
    for (int e = e0 + threadIdx.x; e < e1; e += 256) {
      int s = ei[e];
      int d = ei[NEDGES + e];
      atomicAdd(&h[d >> 7], 1);
      atomicAdd(&h[s >> 7], 1);
    }
    __syncthreads();
    for (int i = threadIdx.x; i < NB; i += 256)
      cntg[b * NB + i] = h[i];
  } else {
    const int b = bid - 26024;
    const int k = b >> 6;
    const int chunk = b & 63;
    const float* wk = w + (size_t)k * 65536 + chunk * 1024;
    float m = 0.f;
    #pragma unroll
    for (int i = 0; i < 4; ++i) m = fmaxf(m, fabsf(wk[threadIdx.x + i * 256]));
    #pragma unroll
    for (int i = 1; i < 64; i <<= 1) m = fmaxf(m, __shfl_xor(m, i, 64));
    if (threadIdx.x == 0) h[0] = 0;
    __syncthreads();
    if ((threadIdx.x & 63) == 0) atomicMax(&h[0], __float_as_int(m));
    __syncthreads();
    if (threadIdx.x == 0) atomicMax(&dWmax[k], (unsigned int)h[0]);
  }
}

// ---------------- CSR back-end (r9/r11 config) ----------------

__global__ __launch_bounds__(256)
void scan_chunks_kernel(int* __restrict__ cntg, int* __restrict__ tot) {
  __shared__ int ws2[4];
  const int v = blockIdx.x;
  const int t = threadIdx.x, lane = t & 63, wv = t >> 6;
  int c[4];
  int sum = 0;
  #pragma unroll
  for (int i = 0; i < 4; ++i) { c[i] = cntg[(4 * t + i) * NB + v]; sum += c[i]; }
  int s = sum;
  #pragma unroll
  for (int off = 1; off < 64; off <<= 1) {
    int tmp = __shfl_up(s, off, 64);
    if (lane >= off) s += tmp;
  }
  if (lane == 63) ws2[wv] = s;
  __syncthreads();
  int wpre = 0;
  #pragma unroll
  for (int k = 0; k < 4; ++k) wpre += (k < wv) ? ws2[k] : 0;
  int run = wpre + s - sum;
  #pragma unroll
  for (int i = 0; i < 4; ++i) { int tmp = c[i]; cntg[(4 * t + i) * NB + v] = run; run += tmp; }
  if (t == 255) tot[v] = wpre + s;
}

__global__ __launch_bounds__(1024)
void base_scan_kernel(const int* __restrict__ tot, int* __restrict__ bbase) {
  __shared__ int ws[16];
  int t = threadIdx.x, lane = t & 63, wv = t >> 6;
  int v = (t < NB) ? tot[t] : 0;
  int s = v;
  #pragma unroll
  for (int off = 1; off < 64; off <<= 1) {
    int tmp = __shfl_up(s, off, 64);
    if (lane >= off) s += tmp;
  }
  if (lane == 63) ws[wv] = s;
  __syncthreads();
  if (t == 0) {
    int run = 0;
    #pragma unroll
    for (int k = 0; k < 16; ++k) { int tmp = ws[k]; ws[k] = run; run += tmp; }
  }
  __syncthreads();
  int excl = s + ws[wv] - v;
  if (t < NB) bbase[t] = excl;
  if (t == NB) bbase[NB] = excl;
}

// packed binned entry: (owner&127)<<17 | nbr
__global__ __launch_bounds__(256)
void fill_kernel(const int* __restrict__ ei, const int* __restrict__ cntg,
                 const int* __restrict__ bbase, unsigned int* __restrict__ binned) {
  __shared__ int cur[NB];
  const int b = blockIdx.x;
  for (int i = threadIdx.x; i < NB; i += 256)
    cur[i] = bbase[i] + cntg[b * NB + i];
  __syncthreads();
  const int e0 = b * CHUNK;
  const int e1 = (e0 + CHUNK < NEDGES) ? e0 + CHUNK : NEDGES;
  for (int e = e0 + threadIdx.x; e < e1; e += 256) {
    int s = ei[e];
    int d = ei[NEDGES + e];
    int p = atomicAdd(&cur[d >> 7], 1);
    binned[p] = ((unsigned int)(d & 127) << 17) | (unsigned int)s;
    int q = atomicAdd(&cur[s >> 7], 1);
    binned[q] = ((unsigned int)(s & 127) << 17) | (unsigned int)d;
  }
}

// adj entries are PRE-SCALED q-row byte offsets (nbr * 256).
__global__ __launch_bounds__(256)
void bucket_csr_kernel(const unsigned int* __restrict__ binned,
                       const int* __restrict__ bbase,
                       int* __restrict__ row_ptr, int* __restrict__ adj) {
  __shared__ int cnt[128];
  __shared__ int cur[128];
  const int b = blockIdx.x;
  const int node0 = b << 7;
  const int base = bbase[b];
  const int end = bbase[b + 1];
  const int tid = threadIdx.x;
  if (tid < 128) cnt[tid] = 0;
  __syncthreads();
  for (int i = base + tid; i < end; i += 256) {
    unsigned int v = binned[i];
    atomicAdd(&cnt[v >> 17], 1);
  }
  __syncthreads();
  if (tid < 128) {
    int ex = 0;
    #pragma unroll 8
    for (int j = 0; j < 128; ++j) {
      int c = cnt[j];
      ex += (j < tid) ? c : 0;
    }
    int node = node0 + tid;
    if (node < NNODES) row_ptr[node] = base + ex;
    cur[tid] = base + ex;
  }
  if (tid == 0 && b == NB - 1) row_ptr[NNODES] = end;
  __syncthreads();
  for (int i = base + tid; i < end; i += 256) {
    unsigned int v = binned[i];
    int nbr = (int)(v & 0x1FFFFu);
    int p = atomicAdd(&cur[v >> 17], 1);
    adj[p] = nbr << 8;
  }
}

// ---------------- quantw ----------------
__global__ void quantw_kernel(const float* __restrict__ w,
                              const unsigned int* __restrict__ dWmax,
                              signed char* __restrict__ W8) {
  int idx = blockIdx.x * 256 + threadIdx.x;
  int k = idx >> 16, f = (idx >> 8) & 255, o = idx & 255;
  float mx = __uint_as_float(dWmax[k]);
  float inv = (mx > 0.f) ? 127.f / mx : 0.f;
  W8[(size_t)k * 65536 + o * 256 + f] = (signed char)(int)__builtin_rintf(w[idx] * inv);
}

// ---------------- SpMM int8 (gather, wave/node, unroll 8) ----------------
// Signed int8 storage; decode via biased-ubyte trick; bias 128*sum(s)
// subtracted at end. wid readfirstlane'd so row_ptr loads go scalar.
// 8 gathers + 8 scale loads issued before decode -> ~2KB in flight/wave.

#define DECQ(vv, ss)                                        \
  { acc0 += (ss) * (float)((vv) & 255u);                    \
    acc1 += (ss) * (float)(((vv) >> 8) & 255u);             \
    acc2 += (ss) * (float)(((vv) >> 16) & 255u);            \
    acc3 += (ss) * (float)((vv) >> 24);                     \
    ssum += (ss); }

__global__ __launch_bounds__(256)
void spmm_q8_kernel(const unsigned char* __restrict__ gin,   // [N][256] int8
                    const float* __restrict__ sin,           // [N] scales
                    unsigned char* __restrict__ gout,        // [N][256] int8
                    float* __restrict__ sout,                // [N]
                    const int* __restrict__ row_ptr,
                    const int* __restrict__ adjb) {
  const int wid = __builtin_amdgcn_readfirstlane((blockIdx.x * 256 + threadIdx.x) >> 6);
  const int lane = threadIdx.x & 63;
  if (wid >= NNODES) return;
  const int beg = row_ptr[wid];
  const int end = row_ptr[wid + 1];
  const int lb = lane << 2;
  const char* scb = (const char*)sin;

  float acc0 = 0.f, acc1 = 0.f, acc2 = 0.f, acc3 = 0.f, ssum = 0.f;
  int j = beg;
  for (; j + 8 <= end; j += 8) {
    int o0 = adjb[j + 0], o1 = adjb[j + 1], o2 = adjb[j + 2], o3 = adjb[j + 3];
    int o4 = adjb[j + 4], o5 = adjb[j + 5], o6 = adjb[j + 6], o7 = adjb[j + 7];
    unsigned int v0 = *(const unsigned int*)(gin + o0 + lb) ^ 0x80808080u;
    unsigned int v1 = *(const unsigned int*)(gin + o1 + lb) ^ 0x80808080u;
    unsigned int v2 = *(const unsigned int*)(gin + o2 + lb) ^ 0x80808080u;
    unsigned int v3 = *(const unsigned int*)(gin + o3 + lb) ^ 0x80808080u;
    unsigned int v4 = *(const unsigned int*)(gin + o4 + lb) ^ 0x80808080u;
    unsigned int v5 = *(const unsigned int*)(gin + o5 + lb) ^ 0x80808080u;
    unsigned int v6 = *(const unsigned int*)(gin + o6 + lb) ^ 0x80808080u;
    unsigned int v7 = *(const unsigned int*)(gin + o7 + lb) ^ 0x80808080u;
    float s0 = *(const float*)(scb + (o0 >> 6));
    float s1 = *(const float*)(scb + (o1 >> 6));
    float s2 = *(const float*)(scb + (o2 >> 6));
    float s3 = *(const float*)(scb + (o3 >> 6));
    float s4 = *(const float*)(scb + (o4 >> 6));
    float s5 = *(const float*)(scb + (o5 >> 6));
    float s6 = *(const float*)(scb + (o6 >> 6));
    float s7 = *(const float*)(scb + (o7 >> 6));
    DECQ(v0, s0); DECQ(v1, s1); DECQ(v2, s2); DECQ(v3, s3);
    DECQ(v4, s4); DECQ(v5, s5); DECQ(v6, s6); DECQ(v7, s7);
  }
  for (; j < end; ++j) {
    int o = adjb[j];
    float s = *(const float*)(scb + (o >> 6));
    unsigned int v = *(const unsigned int*)(gin + o + lb) ^ 0x80808080u;
    DECQ(v, s);
  }

  const float bias = 128.f * ssum;
  const float a0 = acc0 - bias;
  const float a1 = acc1 - bias;
  const float a2 = acc2 - bias;
  const float a3 = acc3 - bias;

  float m = fmaxf(fmaxf(fabsf(a0), fabsf(a1)), fmaxf(fabsf(a2), fabsf(a3)));
  #pragma unroll
  for (int i = 1; i < 64; i <<= 1) m = fmaxf(m, __shfl_xor(m, i, 64));
  float inv = (m > 0.f) ? 127.f / m : 0.f;
  int q0 = (int)__builtin_rintf(a0 * inv);
  int q1 = (int)__builtin_rintf(a1 * inv);
  int q2 = (int)__builtin_rintf(a2 * inv);
  int q3 = (int)__builtin_rintf(a3 * inv);
  *(unsigned int*)(gout + (size_t)wid * 256 + lb) =
      ((unsigned)q0 & 255u) | (((unsigned)q1 & 255u) << 8) |
      (((unsigned)q2 & 255u) << 16) | (((unsigned)q3 & 255u) << 24);
  if (lane == 0) sout[wid] = m * (1.f / 127.f);
}

// ---------------- GEMM: 4x { [128,256]i8 @ [256,256]i8 } -> fp32 ----------------
// r11 version (LDS XOR-swizzle both-sides; private-LDS staged full-line
// C stores).

__global__ __launch_bounds__(512)
void gemm_i8_kernel(const unsigned char* __restrict__ q0p,
                    const unsigned char* __restrict__ q1p,
                    const unsigned char* __restrict__ q2p,
                    const unsigned char* __restrict__ q3p,
                    const float* __restrict__ s0p,
                    const float* __restrict__ s1p,
                    const float* __restrict__ s2p,
                    const float* __restrict__ s3p,
                    const signed char* __restrict__ W8,     // [4][256][256]
                    const unsigned int* __restrict__ dWmax, // [4]
                    float* __restrict__ C) {                // [NNODES][256]
  __shared__ __align__(16) unsigned char smem[49152];       // As 16K | Bs 32K
  unsigned char* As = smem;
  unsigned char* Bs = smem + 16384;
  const int tid = threadIdx.x;
  const int lane = tid & 63;
  const int wave = tid >> 6;
  const int wr = wave >> 2;
  const int wc = wave & 3;
  const int rowA_base = blockIdx.x * 128;

  const unsigned char* qs[4] = {q0p, q1p, q2p, q3p};
  const float* scs[4] = {s0p, s1p, s2p, s3p};

  f32x4 accf[4][4] = {};

  #pragma unroll
  for (int k = 0; k < 4; ++k) {
    const unsigned char* Qk = qs[k];
    const signed char* Wk = W8 + (size_t)k * 65536;
    i32x4 acci[4][4] = {};
    #pragma unroll
    for (int kc = 0; kc < 2; ++kc) {
      __syncthreads();
      #pragma unroll
      for (int i = 0; i < 2; ++i) {
        int slot = tid + 512 * i;
        int row = slot >> 3;
        int col = ((slot & 7) << 4) ^ ((row & 7) << 4);
        async_ld16(Qk + (size_t)(rowA_base + row) * 256 + kc * 128 + col,
                   &As[slot * 16]);
      }
      #pragma unroll
      for (int i = 0; i < 4; ++i) {
        int slot = tid + 512 * i;
        int row = slot >> 3;
        int col = ((slot & 7) << 4) ^ ((row & 7) << 4);
        async_ld16(Wk + (size_t)row * 256 + kc * 128 + col, &Bs[slot * 16]);
      }
      __syncthreads();
      #pragma unroll
      for (int kk = 0; kk < 2; ++kk) {
        const int kb = kk * 64 + ((lane >> 4) << 4);
        i32x4 a[4], b[4];
        #pragma unroll
        for (int m = 0; m < 4; ++m) {
          int row = wr * 64 + m * 16 + (lane & 15);
          a[m] = *(const i32x4*)&As[row * 128 + (kb ^ ((row & 7) << 4))];
        }
        #pragma unroll
        for (int n = 0; n < 4; ++n) {
          int row = wc * 64 + n * 16 + (lane & 15);
          b[n] = *(const i32x4*)&Bs[row * 128 + (kb ^ ((row & 7) << 4))];
        }
        #pragma unroll
        for (int m = 0; m < 4; ++m) {
          #pragma unroll
          for (int n = 0; n < 4; ++n)
            acci[m][n] = __builtin_amdgcn_mfma_i32_16x16x64_i8(a[m], b[n], acci[m][n], 0, 0, 0);
        }
      }
    }
    const float dWk = __uint_as_float(dWmax[k]) * (1.f / 127.f);
    const float* sk = scs[k];
    #pragma unroll
    for (int m = 0; m < 4; ++m) {
      #pragma unroll
      for (int j = 0; j < 4; ++j) {
        int r = rowA_base + wr * 64 + ((lane >> 4) << 2) + m * 16 + j;
        float s = sk[r] * dWk;
        #pragma unroll
        for (int n = 0; n < 4; ++n)
          accf[m][n][j] += s * (float)acci[m][n][j];
      }
    }
  }

  __syncthreads();
  float* myCs = (float*)smem + wave * 1056;   // [16 rows][stride 66]
  #pragma unroll
  for (int m = 0; m < 4; ++m) {
    #pragma unroll
    for (int n = 0; n < 4; ++n) {
      #pragma unroll
      for (int j = 0; j < 4; ++j)
        myCs[(((lane >> 4) << 2) | j) * 66 + (lane & 15) + n * 16] = accf[m][n][j];
    }
    #pragma unroll
    for (int it = 0; it < 4; ++it) {
      int row = it * 4 + (lane >> 4);
      f32x4 v = *(const f32x4*)&myCs[row * 66 + ((lane & 15) << 2)];
      int r = rowA_base + wr * 64 + m * 16 + row;
      if (r < NNODES)
        *(f32x4*)&C[(size_t)r * FOUTF + wc * 64 + ((lane & 15) << 2)] = v;
    }
  }
}

// ---------------- launch ----------------

extern "C" void kernel_launch(void* const* d_in, const int* in_sizes, int n_in,
                              void* d_out, int out_size, void* d_ws, size_t ws_size,
                              hipStream_t stream) {
  (void)in_sizes; (void)n_in; (void)out_size; (void)ws_size;
  const float* x  = (const float*)d_in[0];
  const int*   ei = (const int*)d_in[1];
  const float* w  = (const float*)d_in[2];
  float* out = (float*)d_out;

  char* ws = (char*)d_ws;
  size_t off = 0;
  auto carve = [&](size_t bytes) -> void* {
    void* p = ws + off;
    off = (off + bytes + 255) & ~(size_t)255;
    return p;
  };
  unsigned char* gA = (unsigned char*)carve((size_t)MPAD * 256);   // 25.6 MB
  unsigned char* gB = (unsigned char*)carve((size_t)MPAD * 256);
  unsigned char* gC = (unsigned char*)carve((size_t)MPAD * 256);
  unsigned char* gD = (unsigned char*)carve((size_t)MPAD * 256);
  float* scA        = (float*)carve((size_t)MPAD * 4);
  float* scB        = (float*)carve((size_t)MPAD * 4);
  float* scC        = (float*)carve((size_t)MPAD * 4);
  float* scD        = (float*)carve((size_t)MPAD * 4);
  signed char* W8   = (signed char*)carve((size_t)4 * 65536);
  unsigned int* dWmax = (unsigned int*)carve(4 * 4);
  int* row_ptr      = (int*)carve((size_t)(NNODES + 1) * 4);
  int* adj          = (int*)carve((size_t)2 * NEDGES * 4);         // 25.6 MB
  int* cntg         = (int*)carve((size_t)NCHUNK * NB * 4);        // 3.2 MB
  int* tot          = (int*)carve((size_t)NB * 4);
  int* bbase        = (int*)carve((size_t)(NB + 1) * 4);
  // binned (2E * 4B = 25.6 MB) aliases gD: fully consumed by bucket_csr
  // before hop3 writes q3 into gD (stream-ordered).
  unsigned int* binned = (unsigned int*)gD;

  hipMemsetAsync(dWmax, 0, 16, stream);

  front_kernel<<<26280, 256, 0, stream>>>(x, gA, scA, ei, cntg, w, dWmax);
  scan_chunks_kernel<<<NB, 256, 0, stream>>>(cntg, tot);
  base_scan_kernel<<<1, 1024, 0, stream>>>(tot, bbase);
  fill_kernel<<<NCHUNK, 256, 0, stream>>>(ei, cntg, bbase, binned);
  bucket_csr_kernel<<<NB, 256, 0, stream>>>(binned, bbase, row_ptr, adj);
  quantw_kernel<<<1024, 256, 0, stream>>>(w, dWmax, W8);

  // hop1: q0->q1; hop2: q1->q2; hop3: q2->q3
  spmm_q8_kernel<<<25000, 256, 0, stream>>>(gA, scA, gB, scB, row_ptr, adj);
  spmm_q8_kernel<<<25000, 256, 0, stream>>>(gB, scB, gC, scC, row_ptr, adj);
  spmm_q8_kernel<<<25000, 256, 0, stream>>>(gC, scC, gD, scD, row_ptr, adj);

  gemm_i8_kernel<<<MTILES, 512, 0, stream>>>(gA, gB, gC, gD, scA, scB, scC, scD,
                                             W8, dWmax, out);
}